// Round 1
// baseline (505.330 us; speedup 1.0000x reference)
//
#include <hip/hip_runtime.h>

#define DEVI __device__ __forceinline__

typedef _Float16 h16;
typedef h16 h16x8 __attribute__((ext_vector_type(8)));
typedef h16 h16x4 __attribute__((ext_vector_type(4)));
typedef float f32x4 __attribute__((ext_vector_type(4)));
typedef unsigned short u16;
typedef u16 u16x8 __attribute__((ext_vector_type(8)));
typedef u16 u16x4 __attribute__((ext_vector_type(4)));

constexpr int Bc = 2, Sc = 2048, Dc = 2048, HQc = 32, HKVc = 8, HDc = 64;

DEVI u16 f2h(float f){ h16 h = (h16)f; return __builtin_bit_cast(u16, h); }
DEVI float h2f(u16 u){ return (float)__builtin_bit_cast(h16, u); }

DEVI f32x4 mfma32(h16x8 a, h16x8 b, f32x4 c){ return __builtin_amdgcn_mfma_f32_16x16x32_f16(a, b, c, 0, 0, 0); }
DEVI f32x4 mfma16(h16x4 a, h16x4 b, f32x4 c){ return __builtin_amdgcn_mfma_f32_16x16x16f16(a, b, c, 0, 0, 0); }

DEVI void glds16(const void* g, void* l){
  __builtin_amdgcn_global_load_lds((__attribute__((address_space(1))) void*)g,
                                   (__attribute__((address_space(3))) void*)l, 16, 0, 0);
}

// ---------------- 1. convert x fp32 -> fp16 ----------------
__global__ __launch_bounds__(256) void convert_x(const float* __restrict__ src, u16* __restrict__ dst){
  size_t i = ((size_t)blockIdx.x * 256 + threadIdx.x) * 8;
  f32x4 a = *(const f32x4*)(src + i);
  f32x4 b = *(const f32x4*)(src + i + 4);
  u16x8 o;
  #pragma unroll
  for (int j = 0; j < 4; ++j){ o[j] = f2h(a[j]); o[4+j] = f2h(b[j]); }
  *(u16x8*)(dst + i) = o;
}

// ---------------- 2. transpose + convert weights: [K][N] f32 -> [N][K] f16 ----------------
__global__ __launch_bounds__(256) void transpose_w(const float* __restrict__ wq, const float* __restrict__ wk,
                                                   const float* __restrict__ wv, const float* __restrict__ wo,
                                                   u16* __restrict__ wqT, u16* __restrict__ wkT,
                                                   u16* __restrict__ wvT, u16* __restrict__ woT){
  __shared__ float tile[32][33];
  int z = blockIdx.z;
  const float* src = (z==0) ? wq : (z==1) ? wk : (z==2) ? wv : wo;
  u16* dst         = (z==0) ? wqT : (z==1) ? wkT : (z==2) ? wvT : woT;
  int N = (z==0 || z==3) ? 2048 : 512;
  int n0 = blockIdx.x * 32;
  if (n0 >= N) return;
  int k0 = blockIdx.y * 32;
  int tx = threadIdx.x, ty = threadIdx.y;
  #pragma unroll
  for (int i = 0; i < 4; ++i)
    tile[ty + i*8][tx] = src[(size_t)(k0 + ty + i*8) * N + n0 + tx];
  __syncthreads();
  #pragma unroll
  for (int i = 0; i < 4; ++i){
    int nn = ty + i*8;
    dst[(size_t)(n0 + nn) * 2048 + k0 + tx] = f2h(tile[tx][nn]);
  }
}

// ---------------- 3/6. GEMM: C[4096 x N] = A[4096 x 2048] @ W^T rows ----------------
// MODE 0: N=3072 (wq|wk|wv), epilogue scatters to per-head Q/K/V fp16.
// MODE 1: N=2048 (wo), epilogue writes fp32 d_out.
template<int MODE>
__global__ __launch_bounds__(256) void gemm_k(const u16* __restrict__ A,
    const u16* __restrict__ W0, const u16* __restrict__ W1, const u16* __restrict__ W2,
    u16* __restrict__ Qb, u16* __restrict__ Kb, u16* __restrict__ Vb, float* __restrict__ Out){
  __shared__ u16 ldsA[128 * 64];
  __shared__ u16 ldsB[128 * 64];
  int tid = threadIdx.x, wv_ = tid >> 6, l = tid & 63, t = l & 15, g = l >> 4;
  int wm = wv_ >> 1, wn = wv_ & 1;
  int m0 = blockIdx.y * 128, n0 = blockIdx.x * 128;
  const u16* Wt; int n0l; int matid;
  if (MODE == 1){ Wt = W0; n0l = n0; matid = 0; }
  else {
    if (n0 < 2048)      { Wt = W0; n0l = n0;        matid = 0; }
    else if (n0 < 2560) { Wt = W1; n0l = n0 - 2048; matid = 1; }
    else                { Wt = W2; n0l = n0 - 2560; matid = 2; }
  }
  f32x4 acc[4][4] = {};
  int lr = l >> 3, lc = l & 7;
  for (int kk = 0; kk < 32; ++kk){
    int k0 = kk * 64;
    #pragma unroll
    for (int i = 0; i < 4; ++i){
      int row = wv_ * 32 + i * 8 + lr;
      int ca = lc ^ (row & 7);            // pre-swizzled global source (rule 21)
      glds16(A  + (size_t)(m0  + row) * 2048 + k0 + ca * 8, &ldsA[(wv_*32 + i*8) * 64]);
      glds16(Wt + (size_t)(n0l + row) * 2048 + k0 + ca * 8, &ldsB[(wv_*32 + i*8) * 64]);
    }
    __syncthreads();
    #pragma unroll
    for (int kf = 0; kf < 2; ++kf){
      h16x8 af[4], bf[4];
      #pragma unroll
      for (int mb = 0; mb < 4; ++mb){
        int r = wm*64 + mb*16 + t;
        af[mb] = *(const h16x8*)&ldsA[r*64 + ((((kf<<2)|g) ^ (r&7)) << 3)];
      }
      #pragma unroll
      for (int nb = 0; nb < 4; ++nb){
        int r = wn*64 + nb*16 + t;
        bf[nb] = *(const h16x8*)&ldsB[r*64 + ((((kf<<2)|g) ^ (r&7)) << 3)];
      }
      #pragma unroll
      for (int mb = 0; mb < 4; ++mb)
        #pragma unroll
        for (int nb = 0; nb < 4; ++nb)
          acc[mb][nb] = mfma32(af[mb], bf[nb], acc[mb][nb]);
    }
    __syncthreads();
  }
  // epilogue: C row = m0 + wm*64 + mb*16 + 4g + r ; col = n0(+l) + wn*64 + nb*16 + t
  if (MODE == 0){
    #pragma unroll
    for (int mb = 0; mb < 4; ++mb){
      int mrow = m0 + wm*64 + mb*16 + (g << 2);
      #pragma unroll
      for (int nb = 0; nb < 4; ++nb){
        int col = n0l + wn*64 + nb*16 + t;
        int h = col >> 6, d = col & 63;
        #pragma unroll
        for (int r = 0; r < 4; ++r){
          int m = mrow + r;
          int bb = m >> 11, s = m & 2047;
          u16 v = f2h(acc[mb][nb][r]);
          if (matid == 0)      Qb[(((size_t)bb*HQc  + h)*Sc + s)*HDc + d] = v;
          else if (matid == 1) Kb[(((size_t)bb*HKVc + h)*Sc + s)*HDc + d] = v;
          else                 Vb[(((size_t)bb*HKVc + h)*Sc + s)*HDc + d] = v;
        }
      }
    }
  } else {
    #pragma unroll
    for (int mb = 0; mb < 4; ++mb){
      int mrow = m0 + wm*64 + mb*16 + (g << 2);
      #pragma unroll
      for (int nb = 0; nb < 4; ++nb){
        int col = n0 + wn*64 + nb*16 + t;
        #pragma unroll
        for (int r = 0; r < 4; ++r)
          Out[(size_t)(mrow + r) * 2048 + col] = acc[mb][nb][r];
      }
    }
  }
}

// ---------------- 4. RoPE on Q and K (in place, fp32 math); folds 1/8 scale into Q ----------------
__global__ __launch_bounds__(256) void rope_k(u16* __restrict__ Qb, u16* __restrict__ Kb,
                                              const float* __restrict__ fcos, const float* __restrict__ fsin){
  int gid = blockIdx.x * 256 + threadIdx.x;        // 1,310,720 threads total
  int row = gid >> 3, seg = gid & 7;
  u16* p; float scale; int s;
  if (row < Bc*HQc*Sc){ p = Qb + (size_t)row*HDc + seg*8; s = row & (Sc-1); scale = 0.125f; }
  else { int r2 = row - Bc*HQc*Sc; p = Kb + (size_t)r2*HDc + seg*8; s = r2 & (Sc-1); scale = 1.0f; }
  u16x8 u = *(u16x8*)p;
  const float* cp = fcos + s*32 + seg*4;
  const float* sp = fsin + s*32 + seg*4;
  u16x8 o;
  #pragma unroll
  for (int i = 0; i < 4; ++i){
    float xr = h2f(u[2*i]), xi = h2f(u[2*i+1]);
    float c = cp[i], sn = sp[i];
    o[2*i]   = f2h((xr*c - xi*sn) * scale);
    o[2*i+1] = f2h((xr*sn + xi*c) * scale);
  }
  *(u16x8*)p = o;
}

// ---------------- 5. causal GQA flash attention ----------------
// block: (qtile of 64 rows, head). 4 waves x 16 q-rows. kv tile = 32.
// Swapped QK^T: S^T = mfma32(K, Q^T)  -> lane holds P for ONE q (col=t), kv = kv0+16*mb+4g+r.
// PV via mfma16: B-frag (k=4g+j) == lane's own P regs; A = V^T from LDS (stride 36, conflict-free).
__global__ __launch_bounds__(256) void attn_k(const u16* __restrict__ Qb, const u16* __restrict__ Kb,
                                              const u16* __restrict__ Vb, u16* __restrict__ Ob){
  __shared__ u16 vlds[64 * 36];
  int tid = threadIdx.x, w = tid >> 6, l = tid & 63, t = l & 15, g = l >> 4;
  int qb = blockIdx.x, head = blockIdx.y;
  int b = head >> 5, hq = head & 31, hkv = hq >> 2;
  int q0 = qb * 64;
  int qrow = q0 + w*16 + t;
  const u16* Qp = Qb + (((size_t)(b*HQc + hq))*Sc + qrow) * HDc;
  h16x8 qf0 = *(const h16x8*)(Qp + g*8);
  h16x8 qf1 = *(const h16x8*)(Qp + 32 + g*8);
  const u16* Kp = Kb + ((size_t)(b*HKVc + hkv)) * Sc * HDc;
  const u16* Vp = Vb + ((size_t)(b*HKVc + hkv)) * Sc * HDc;
  f32x4 o[4] = {};
  float m_run = -1e30f, l_run = 0.0f;
  const float LOG2E = 1.44269504f;
  int ntiles = qb*2 + 2;
  for (int tile = 0; tile < ntiles; ++tile){
    int kv0 = tile * 32;
    // K fragments direct from global (L2-resident: 256 KB/head)
    h16x8 ka00 = *(const h16x8*)(Kp + (size_t)(kv0      + t)*HDc +      g*8);
    h16x8 ka01 = *(const h16x8*)(Kp + (size_t)(kv0      + t)*HDc + 32 + g*8);
    h16x8 ka10 = *(const h16x8*)(Kp + (size_t)(kv0 + 16 + t)*HDc +      g*8);
    h16x8 ka11 = *(const h16x8*)(Kp + (size_t)(kv0 + 16 + t)*HDc + 32 + g*8);
    __syncthreads();                       // prior tile's V reads complete
    {                                      // stage V^T: vlds[d][kv], stride 36
      int kvi = tid >> 3, dseg = tid & 7;
      u16x8 v8 = *(const u16x8*)(Vp + (size_t)(kv0 + kvi)*HDc + dseg*8);
      #pragma unroll
      for (int j = 0; j < 8; ++j) vlds[(dseg*8 + j)*36 + kvi] = v8[j];
    }
    __syncthreads();
    f32x4 s0 = {}, s1 = {};
    s0 = mfma32(ka00, qf0, s0); s0 = mfma32(ka01, qf1, s0);
    s1 = mfma32(ka10, qf0, s1); s1 = mfma32(ka11, qf1, s1);
    // mask + online softmax (scores pre-scaled via Q)
    float p0[4], p1[4];
    float mt = -1e30f;
    #pragma unroll
    for (int r = 0; r < 4; ++r){
      int kv = kv0 + (g<<2) + r;
      float x = (kv <= qrow) ? s0[r] : -1e30f;
      p0[r] = x; mt = fmaxf(mt, x);
    }
    #pragma unroll
    for (int r = 0; r < 4; ++r){
      int kv = kv0 + 16 + (g<<2) + r;
      float x = (kv <= qrow) ? s1[r] : -1e30f;
      p1[r] = x; mt = fmaxf(mt, x);
    }
    mt = fmaxf(mt, __shfl_xor(mt, 16));
    mt = fmaxf(mt, __shfl_xor(mt, 32));
    float m_new = fmaxf(m_run, mt);
    float alpha = exp2f((m_run - m_new) * LOG2E);
    float rs = 0.0f;
    #pragma unroll
    for (int r = 0; r < 4; ++r){ p0[r] = exp2f((p0[r] - m_new)*LOG2E); rs += p0[r]; }
    #pragma unroll
    for (int r = 0; r < 4; ++r){ p1[r] = exp2f((p1[r] - m_new)*LOG2E); rs += p1[r]; }
    rs += __shfl_xor(rs, 16); rs += __shfl_xor(rs, 32);
    l_run = l_run * alpha + rs;
    m_run = m_new;
    #pragma unroll
    for (int db = 0; db < 4; ++db)
      #pragma unroll
      for (int r = 0; r < 4; ++r) o[db][r] *= alpha;
    h16x4 pf0, pf1;
    #pragma unroll
    for (int j = 0; j < 4; ++j){ pf0[j] = (h16)p0[j]; pf1[j] = (h16)p1[j]; }
    #pragma unroll
    for (int db = 0; db < 4; ++db){
      const u16* vp = &vlds[(db*16 + t)*36 + (g<<2)];
      h16x4 vf0 = *(const h16x4*)vp;
      h16x4 vf1 = *(const h16x4*)(vp + 16);
      o[db] = mfma16(vf0, pf0, o[db]);     // O^T[d][q] += V^T @ P^T  (kv 0..15)
      o[db] = mfma16(vf1, pf1, o[db]);     // (kv 16..31)
    }
  }
  float inv = 1.0f / l_run;
  u16* Op = Ob + ((size_t)(b*Sc + qrow)) * Dc + hq*HDc;
  #pragma unroll
  for (int db = 0; db < 4; ++db){
    u16x4 st;
    #pragma unroll
    for (int r = 0; r < 4; ++r) st[r] = f2h(o[db][r] * inv);
    *(u16x4*)(Op + db*16 + (g<<2)) = st;
  }
}

// ---------------- launch ----------------
extern "C" void kernel_launch(void* const* d_in, const int* in_sizes, int n_in,
                              void* d_out, int out_size, void* d_ws, size_t ws_size,
                              hipStream_t stream){
  const float* x    = (const float*)d_in[0];
  const float* fcos = (const float*)d_in[1];
  const float* fsin = (const float*)d_in[2];
  const float* wq   = (const float*)d_in[3];
  const float* wk   = (const float*)d_in[4];
  const float* wv   = (const float*)d_in[5];
  const float* wo   = (const float*)d_in[6];
  float* out = (float*)d_out;

  u16* ws  = (u16*)d_ws;
  u16* x16 = ws;                    // 8,388,608  (also reused as attn-out Ob after gemm<0>)
  u16* wqT = x16 + 8388608;         // 4,194,304
  u16* wkT = wqT + 4194304;         // 1,048,576
  u16* wvT = wkT + 1048576;         // 1,048,576
  u16* woT = wvT + 1048576;         // 4,194,304
  u16* Qb  = woT + 4194304;         // 8,388,608
  u16* Kb  = Qb  + 8388608;         // 2,097,152
  u16* Vb  = Kb  + 2097152;         // 2,097,152  -> total 31,457,280 u16 = 63 MB
  u16* Ob  = x16;                   // alias: x16 is dead after gemm<0>

  convert_x  <<<4096, 256, 0, stream>>>(x, x16);
  transpose_w<<<dim3(64,64,4), dim3(32,8), 0, stream>>>(wq, wk, wv, wo, wqT, wkT, wvT, woT);
  gemm_k<0>  <<<dim3(24,32), 256, 0, stream>>>(x16, wqT, wkT, wvT, Qb, Kb, Vb, nullptr);
  rope_k     <<<5120, 256, 0, stream>>>(Qb, Kb, fcos, fsin);
  attn_k     <<<dim3(32,64), 256, 0, stream>>>(Qb, Kb, Vb, Ob);
  gemm_k<1>  <<<dim3(16,32), 256, 0, stream>>>(Ob, woT, nullptr, nullptr, nullptr, nullptr, nullptr, out);
}